// Round 12
// baseline (213.911 us; speedup 1.0000x reference)
//
#include <hip/hip_runtime.h>
#include <cstdint>
#include <cstddef>

#define DEV static __device__ __forceinline__

typedef __attribute__((ext_vector_type(8))) short bf16x8;   // 8 bf16 (4 VGPRs)
typedef __attribute__((ext_vector_type(4))) float f32x4;

constexpr int NB   = 64;     // batch
constexpr int NTOK = 197;    // tokens
constexpr int DIMC = 768;    // channels
constexpr int NH   = 12;     // heads
constexpr int HDIM = 64;     // head dim
constexpr int MTOK = NB * NTOK;   // 12608 rows
constexpr int QKVO = 3 * DIMC;    // 2304
constexpr int BH   = NB * NH;     // 768
constexpr int KROWS = 198;        // staged K rows (jrow clamped to 197)
constexpr int VTS   = 232;        // V^T row stride (464B, 16B-aligned)
constexpr int OBS   = 68;         // O-bounce row stride (136B)
constexpr int GM64  = MTOK / 64;  // 197 M-tiles (64-row, exact)

// ---- qkv geometry (R5 schedule, R12 fused-cvt A): 128x128, BK=64, dbuf, 2 blk/CU ----
// R11's BK=32 triple-buffer REVERTED: 68 µs (per-kt fixed costs dominate at
// 24 K-tiles; granularity tax > 3-block TLP gain). Scheduling exhausted at 55;
// R12 removes WORK instead: A staged directly from f32 x (reg+cvt_pk+ds_write),
// killing cvt_all's x-pass (58 MB traffic + a kernel dependency).
constexpr int GMQ  = (MTOK + 127) / 128;   // 99 M-tiles
constexpr int GNQ  = QKVO / 128;           // 18 N-tiles
constexpr int NKT  = DIMC / 64;            // 12 K-tiles
constexpr int HBUF = 16384;                // ushorts per buffer (A 8K + B 8K elems)

// ---- proj geometry (R6, frozen): 64x128 tile, BK=64, dbuf 48KB -> 3 blk/CU ----
constexpr int PBUF = 12288;                // ushorts per buffer (A 4K + B 8K elems)

DEV unsigned short f2bf(float f) {
  union { float f; uint32_t u; } v; v.f = f;
  uint32_t u = v.u;
  return (unsigned short)((u + 0x7FFFu + ((u >> 16) & 1u)) >> 16);  // RNE, finite
}

// R10: single-op packed f32->bf16 (RNE, bit-identical to f2bf on finite values).
DEV uint32_t pack_bf2(float a, float b) {
  uint32_t r;
  asm("v_cvt_pk_bf16_f32 %0, %1, %2" : "=v"(r) : "v"(a), "v"(b));
  return r;   // a -> bits 0..15, b -> bits 16..31
}

DEV f32x4 mfma16(bf16x8 a, bf16x8 b, f32x4 c) {
  return __builtin_amdgcn_mfma_f32_16x16x32_bf16(a, b, c, 0, 0, 0);
}

DEV void async_cp16(const unsigned short* g, unsigned short* l) {
  __builtin_amdgcn_global_load_lds(
      (__attribute__((address_space(1))) void*)g,
      (__attribute__((address_space(3))) void*)l, 16, 0, 0);
}

// supertile swizzle: groups of 16 M-tiles, N-major inside the group.
DEV void swizzle_idx(int lin, int gridM, int gridN, int& mt, int& nt) {
  int per = 16 * gridN;
  int sup = lin / per;
  int bm  = sup * 16;
  int Gm  = gridM - bm; if (Gm > 16) Gm = 16;
  int rem = lin - sup * per;
  nt = rem / Gm;
  mt = bm + (rem - nt * Gm);
}

// ---------------- f32 -> bf16 converts (R12: WEIGHTS ONLY) ----------------
constexpr int CVB2 = (QKVO * DIMC) / 4096;   //  432 (w_qkv)
constexpr int CVB3 = (DIMC * DIMC) / 4096;   //  144 (w_proj)
constexpr int CVNB = CVB2 + CVB3;            //  576

__global__ void __launch_bounds__(256) cvt_all(const float* __restrict__ wq,
                                               const float* __restrict__ wp,
                                               unsigned short* __restrict__ wqb,
                                               unsigned short* __restrict__ wpb) {
  int blk = blockIdx.x;
  const float* s; unsigned short* d;
  if (blk < CVB2) { s = wq; d = wqb; }
  else            { s = wp; d = wpb; blk -= CVB2; }
  size_t base = (size_t)blk * 4096 + (size_t)threadIdx.x * 4;
#pragma unroll
  for (int j = 0; j < 4; ++j) {
    size_t i = base + (size_t)j * 1024;
    float4 f = *(const float4*)(s + i);
    ushort4 o;
    o.x = f2bf(f.x); o.y = f2bf(f.y); o.z = f2bf(f.z); o.w = f2bf(f.w);
    *(ushort4*)(d + i) = o;
  }
}

// ---------------- QKV GEMM: 128x128 dbuf; A reg-staged from f32 x (R12) ------------
// A: each thread owns 4 chunks (c = u*256+tid); chunk c = LDS row c>>3,
// slot c&7, holding global 8-elem unit (slot ^ (row&7)) — same layout the
// ldAB reader expects. f32 load -> cvt_pk -> ds_write_b128 (dest swizzle is
// fine for ds_write; only global_load_lds needs linear dests).
DEV void stage_A_load(const float* __restrict__ X, int mbase, int k0, int tid,
                      float4 (&ld)[4][2]) {
#pragma unroll
  for (int u = 0; u < 4; ++u) {
    int c = u * 256 + tid;
    int row = c >> 3, cc = c & 7;
    int gr = mbase + row; gr = gr < MTOK ? gr : MTOK - 1;   // M tail clamp
    int gc = (cc ^ (row & 7)) * 8;
    const float* p = X + (size_t)gr * DIMC + k0 + gc;
    ld[u][0] = *(const float4*)(p);
    ld[u][1] = *(const float4*)(p + 4);
  }
}

DEV void stage_A_write(unsigned short* dst, int tid, float4 (&ld)[4][2]) {
#pragma unroll
  for (int u = 0; u < 4; ++u) {
    int c = u * 256 + tid;
    uint4 w;
    w.x = pack_bf2(ld[u][0].x, ld[u][0].y);
    w.y = pack_bf2(ld[u][0].z, ld[u][0].w);
    w.z = pack_bf2(ld[u][1].x, ld[u][1].y);
    w.w = pack_bf2(ld[u][1].z, ld[u][1].w);
    *(uint4*)(dst + c * 8) = w;
  }
}

// B: gload_lds staging (R5 form)
DEV void stage_B(const unsigned short* src, unsigned short* dst,
                 int rbase, int k0, int tid) {
#pragma unroll
  for (int u = 0; u < 4; ++u) {
    int c = u * 256 + tid;
    int row = c >> 3, cc = c & 7;
    int gc = (cc ^ (row & 7)) * 8;
    async_cp16(src + (size_t)(rbase + row) * DIMC + k0 + gc, dst + c * 8);
  }
}

template <int KK>
DEV void ldAB(const unsigned short* Ac, const unsigned short* Bc,
              int wm, int wn, int l16, int quad,
              bf16x8 (&af)[4], bf16x8 (&bf_)[4]) {
#pragma unroll
  for (int mi = 0; mi < 4; ++mi) {
    int r = wm * 64 + mi * 16 + l16;
    af[mi] = *(const bf16x8*)(Ac + r * 64 + (((KK * 4 + quad) ^ (r & 7)) * 8));
  }
#pragma unroll
  for (int ni = 0; ni < 4; ++ni) {
    int r = wn * 64 + ni * 16 + l16;
    bf_[ni] = *(const bf16x8*)(Bc + r * 64 + (((KK * 4 + quad) ^ (r & 7)) * 8));
  }
}

DEV void mm16(bf16x8 (&af)[4], bf16x8 (&bf_)[4], f32x4 (&acc)[4][4]) {
  __builtin_amdgcn_s_setprio(1);
#pragma unroll
  for (int mi = 0; mi < 4; ++mi)
#pragma unroll
    for (int ni = 0; ni < 4; ++ni)
      acc[mi][ni] = mfma16(af[mi], bf_[ni], acc[mi][ni]);
  __builtin_amdgcn_s_setprio(0);
}

__global__ void __launch_bounds__(256, 2) gemm_qkv(const float* __restrict__ X,
                                                   const unsigned short* __restrict__ Bw,
                                                   unsigned short* __restrict__ qkv) {
  extern __shared__ unsigned short lds[];   // 65536 B: 2 x [A 16KB | B 16KB]
  const int tid = threadIdx.x, lane = tid & 63, wave = tid >> 6;
  const int wm = wave & 1, wn = wave >> 1;        // 2M x 2N waves, 64x64 each
  const int l16 = lane & 15, quad = lane >> 4;
  int mt, nt;
  swizzle_idx(blockIdx.x, GMQ, GNQ, mt, nt);
  const int mbase = mt * 128, nbase = nt * 128;

  f32x4 acc[4][4];
#pragma unroll
  for (int i = 0; i < 4; ++i)
#pragma unroll
    for (int j = 0; j < 4; ++j) acc[i][j] = {0.f, 0.f, 0.f, 0.f};

  unsigned short* A0 = lds;
  unsigned short* B0 = lds + 8192;
  unsigned short* A1 = lds + HBUF;
  unsigned short* B1 = lds + HBUF + 8192;

  float4 ald[4][2];

  // prologue: A kt0 via reg+cvt, B kt0 via gload_lds; drain; barrier
  stage_A_load(X, mbase, 0, tid, ald);           // 8 vm loads (issued first)
  stage_B(Bw, B0, nbase, 0, tid);                // 4 gload_lds
  asm volatile("s_waitcnt vmcnt(4)" ::: "memory");   // A loads complete
  stage_A_write(A0, tid, ald);
  asm volatile("s_waitcnt vmcnt(0) lgkmcnt(0)" ::: "memory");
  __builtin_amdgcn_s_barrier();

  for (int kt = 0; kt < NKT; ++kt) {
    const unsigned short* Ac = (kt & 1) ? A1 : A0;
    const unsigned short* Bc = (kt & 1) ? B1 : B0;
    unsigned short* An = (kt & 1) ? A0 : A1;
    unsigned short* Bn = (kt & 1) ? B0 : B1;

    // issue next K-tile's loads up front (A->regs, B->next LDS buffer)
    if (kt + 1 < NKT) {
      int k0n = (kt + 1) * 64;
      stage_A_load(X, mbase, k0n, tid, ald);
      stage_B(Bw, Bn, nbase, k0n, tid);
    }

    // free-running compute; co-SIMD wave from the other block anti-phases
    bf16x8 af[4], bf_[4];
    ldAB<0>(Ac, Bc, wm, wn, l16, quad, af, bf_);
    mm16(af, bf_, acc);
    ldAB<1>(Ac, Bc, wm, wn, l16, quad, af, bf_);
    mm16(af, bf_, acc);

    // write A-next (loads landed long ago), then boundary drain + barrier
    if (kt + 1 < NKT) {
      asm volatile("s_waitcnt vmcnt(4)" ::: "memory");   // my 8 A loads done
      stage_A_write(An, tid, ald);
      asm volatile("s_waitcnt vmcnt(0) lgkmcnt(0)" ::: "memory");
      __builtin_amdgcn_s_barrier();
    }
  }

  // epilogue: scatter to qkv bf16 [3][B][H][N][HD]
  const int oc64  = nbase + wn * 64;   // 64-aligned -> uniform which/h per wave
  const int which = oc64 / DIMC;
  const int h     = (oc64 % DIMC) / HDIM;
#pragma unroll
  for (int mi = 0; mi < 4; ++mi) {
    int t0 = mbase + wm * 64 + mi * 16 + quad * 4;
#pragma unroll
    for (int r = 0; r < 4; ++r) {
      int t = t0 + r;
      if (t < MTOK) {
        int b = t / NTOK, n = t - b * NTOK;
        size_t base = ((size_t)((which * NB + b) * NH + h) * NTOK + n) * HDIM;
#pragma unroll
        for (int ni = 0; ni < 4; ++ni)
          qkv[base + ni * 16 + l16] = f2bf(acc[mi][ni][r]);
      }
    }
  }
}

// ---------------- Proj GEMM (R6, frozen): 64x128 dbuf, 3 blocks/CU ----------------
DEV void stage_proj(const unsigned short* A, const unsigned short* Bw,
                    unsigned short* Abuf, unsigned short* Bbuf,
                    int mbase, int nbase, int k0, int tid) {
#pragma unroll
  for (int i = 0; i < 2; ++i) {          // A: 512 x 16B chunks (64 rows)
    int c = i * 256 + tid;
    int row = c >> 3, cc = c & 7;
    int gc = (cc ^ (row & 7)) * 8;
    async_cp16(A + (size_t)(mbase + row) * DIMC + k0 + gc, Abuf + c * 8);
  }
#pragma unroll
  for (int i = 0; i < 4; ++i) {          // B: 1024 x 16B chunks (128 rows)
    int c = i * 256 + tid;
    int row = c >> 3, cc = c & 7;
    int gc = (cc ^ (row & 7)) * 8;
    async_cp16(Bw + (size_t)(nbase + row) * DIMC + k0 + gc, Bbuf + c * 8);
  }
}

__global__ void __launch_bounds__(256, 3) gemm_proj(const unsigned short* __restrict__ A,
                                                    const unsigned short* __restrict__ Bw,
                                                    const float* __restrict__ bias,
                                                    const float* __restrict__ xres,
                                                    float* __restrict__ out) {
  extern __shared__ unsigned short lds[];   // 49152 B: 2 x [A 8KB | B 16KB]
  const int tid = threadIdx.x, lane = tid & 63, wave = tid >> 6;
  const int wm = wave & 1, wn = wave >> 1;
  const int l16 = lane & 15, quad = lane >> 4;
  int mt, nt;
  swizzle_idx(blockIdx.x, GM64, DIMC / 128, mt, nt);
  const int mbase = mt * 64, nbase = nt * 128;   // MTOK = 197*64 exactly: no tail

  f32x4 acc[2][4];
#pragma unroll
  for (int i = 0; i < 2; ++i)
#pragma unroll
    for (int j = 0; j < 4; ++j) acc[i][j] = {0.f, 0.f, 0.f, 0.f};

  unsigned short* A0 = lds;
  unsigned short* B0 = lds + 4096;
  unsigned short* A1 = lds + PBUF;
  unsigned short* B1 = lds + PBUF + 4096;

  // prologue
  stage_proj(A, Bw, A0, B0, mbase, nbase, 0, tid);
  asm volatile("s_waitcnt vmcnt(0)" ::: "memory");
  __builtin_amdgcn_s_barrier();

  for (int kt = 0; kt < NKT; ++kt) {
    const unsigned short* Ac = (kt & 1) ? A1 : A0;
    const unsigned short* Bc = (kt & 1) ? B1 : B0;
    unsigned short* An = (kt & 1) ? A0 : A1;
    unsigned short* Bn = (kt & 1) ? B0 : B1;

    if (kt + 1 < NKT)
      stage_proj(A, Bw, An, Bn, mbase, nbase, (kt + 1) * 64, tid);

#pragma unroll
    for (int kk = 0; kk < 64; kk += 32) {
      const int cw = (kk >> 3) + quad;
      bf16x8 af[2], bfr[4];
#pragma unroll
      for (int mi = 0; mi < 2; ++mi) {
        int r = wm * 32 + mi * 16 + l16;
        af[mi] = *(const bf16x8*)(Ac + r * 64 + ((cw ^ (r & 7)) * 8));
      }
#pragma unroll
      for (int ni = 0; ni < 4; ++ni) {
        int r = wn * 64 + ni * 16 + l16;
        bfr[ni] = *(const bf16x8*)(Bc + r * 64 + ((cw ^ (r & 7)) * 8));
      }
      __builtin_amdgcn_s_setprio(1);
#pragma unroll
      for (int mi = 0; mi < 2; ++mi)
#pragma unroll
        for (int ni = 0; ni < 4; ++ni)
          acc[mi][ni] = mfma16(af[mi], bfr[ni], acc[mi][ni]);
      __builtin_amdgcn_s_setprio(0);
    }

    if (kt + 1 < NKT) {
      asm volatile("s_waitcnt vmcnt(0)" ::: "memory");
      __builtin_amdgcn_s_barrier();
    }
  }

  const int oc = nbase + wn * 64;
#pragma unroll
  for (int mi = 0; mi < 2; ++mi) {
    int t0 = mbase + wm * 32 + mi * 16 + quad * 4;
#pragma unroll
    for (int r = 0; r < 4; ++r) {
      int t = t0 + r;                      // always < MTOK (exact tiling)
      size_t rowb = (size_t)t * DIMC;
#pragma unroll
      for (int ni = 0; ni < 4; ++ni) {
        int o = oc + ni * 16 + l16;
        out[rowb + o] = acc[mi][ni][r] + bias[o] + xres[rowb + o];
      }
    }
  }
}

// ---------------- fused attention (R8 + R10 cvt_pk, frozen): 768 blocks x 8 waves ----
__global__ void __launch_bounds__(512, 2) attn_fused(const unsigned short* __restrict__ qkv,
                                                     const float* __restrict__ scale,
                                                     unsigned short* __restrict__ aout) {
  __shared__ __align__(16) unsigned short Ks[KROWS * 64];        // 25344 B
  __shared__ __align__(16) unsigned short Vt[HDIM * VTS];        // 29696 B
  __shared__ __align__(16) unsigned short Ob[8 * 16 * OBS];      // 17408 B

  const int tid = threadIdx.x, lane = tid & 63, wave = tid >> 6;  // wave 0..7
  const int l16 = lane & 15, quad = lane >> 4;
  const int bh = blockIdx.x;
  const int b = bh / NH, h = bh - b * NH;

  const unsigned short* qg = qkv + (size_t)bh * (NTOK * HDIM);
  const unsigned short* kg = qkv + (size_t)(BH + bh) * (NTOK * HDIM);
  const unsigned short* vg = qkv + (size_t)(2 * BH + bh) * (NTOK * HDIM);
  const float sc = scale[h];

  // stage K via DMA: rows 0..197 (1584 chunks over 512 threads)
#pragma unroll
  for (int i = 0; i < 4; ++i) {
    int c = i * 512 + tid;
    if (c < KROWS * 8) {
      int row = c >> 3, cc = c & 7;
      async_cp16(kg + (size_t)row * 64 + ((cc ^ (row & 7)) * 8), Ks + c * 8);
    }
  }
  // build V^T: coalesced 128B row reads + b128 writes at stride VTS
  {
    const int dcol = tid & 63;
    const int slab = tid >> 6;   // 0..7
#pragma unroll
    for (int p = 0; p < 4; ++p) {
      int n0 = p * 64 + slab * 8;
      if (n0 + 8 <= VTS) {       // PV reads cols < 224 only
        union { unsigned short us[8]; bf16x8 v; } tr;
#pragma unroll
        for (int i = 0; i < 8; ++i) {
          int n = n0 + i; n = n > NTOK - 1 ? NTOK - 1 : n;
          tr.us[i] = vg[(size_t)n * HDIM + dcol];
        }
        *(bf16x8*)(Vt + dcol * VTS + n0) = tr.v;
      }
    }
  }
  __syncthreads();

  const int srcA  = l16 + ((quad & 1) << 5);
  const int srcB  = srcA + 16;
  const int stsel = quad >> 1;
  unsigned short* ob = Ob + wave * (16 * OBS);

  for (int mt = wave; mt < 13; mt += 8) {
    int qr = mt * 16 + l16; if (qr > NTOK - 1) qr = NTOK - 1;
    bf16x8 qb0 = *(const bf16x8*)(qg + (size_t)qr * 64 + quad * 8);
    bf16x8 qb1 = *(const bf16x8*)(qg + (size_t)qr * 64 + 32 + quad * 8);
    const int mg = mt * 16 + l16;

    // batched S^T = K.Q^T (26 MFMAs; jc=6,st=1 keys all masked)
    f32x4 s[7][2];
#pragma unroll
    for (int jc = 0; jc < 7; ++jc)
#pragma unroll
      for (int st = 0; st < 2; ++st) {
        if (jc == 6 && st == 1) { s[6][1] = {0.f, 0.f, 0.f, 0.f}; continue; }
        int jrow = (jc * 2 + st) * 16 + l16;
        jrow = jrow > NTOK ? NTOK : jrow;
        const unsigned short* kr = Ks + jrow * 64;
        bf16x8 ka0 = *(const bf16x8*)(kr + (quad       ^ (jrow & 7)) * 8);
        bf16x8 ka1 = *(const bf16x8*)(kr + ((4 + quad) ^ (jrow & 7)) * 8);
        f32x4 t = {0.f, 0.f, 0.f, 0.f};
        t = mfma16(ka0, qb0, t);
        t = mfma16(ka1, qb1, t);
        s[jc][st] = t;
      }

    // softmax over keys (row = l16)
    float cmax = -1e30f;
#pragma unroll
    for (int jc = 0; jc < 7; ++jc)
#pragma unroll
      for (int st = 0; st < 2; ++st)
#pragma unroll
        for (int r = 0; r < 4; ++r) {
          int jg = jc * 32 + st * 16 + quad * 4 + r;
          float v = s[jc][st][r] * sc;
          v = (jg >= NTOK || jg == mg) ? -1e30f : v;
          s[jc][st][r] = v;
          cmax = fmaxf(cmax, v);
        }
    cmax = fmaxf(cmax, __shfl_xor(cmax, 16));
    cmax = fmaxf(cmax, __shfl_xor(cmax, 32));
    float psum = 0.f;
#pragma unroll
    for (int jc = 0; jc < 7; ++jc)
#pragma unroll
      for (int st = 0; st < 2; ++st)
#pragma unroll
        for (int r = 0; r < 4; ++r) {
          float e = __expf(s[jc][st][r] - cmax);
          psum += e;
          s[jc][st][r] = e;
        }
    psum += __shfl_xor(psum, 16);
    psum += __shfl_xor(psum, 32);
    const float inv = 1.0f / psum;

    // PV: O^T = V^T.P^T; P^T B-frags via shfl, V^T b128 from LDS
    f32x4 oacc[4];
#pragma unroll
    for (int dt = 0; dt < 4; ++dt) oacc[dt] = {0.f, 0.f, 0.f, 0.f};

#pragma unroll
    for (int jc = 0; jc < 7; ++jc) {
      uint32_t u0 = pack_bf2(s[jc][0][0], s[jc][0][1]);
      uint32_t v0 = pack_bf2(s[jc][0][2], s[jc][0][3]);
      uint32_t u1 = pack_bf2(s[jc][1][0], s[jc][1][1]);
      uint32_t v1 = pack_bf2(s[jc][1][2], s[jc][1][3]);
      uint32_t au0 = (uint32_t)__shfl((int)u0, srcA);
      uint32_t av0 = (uint32_t)__shfl((int)v0, srcA);
      uint32_t au1 = (uint32_t)__shfl((int)u1, srcA);
      uint32_t av1 = (uint32_t)__shfl((int)v1, srcA);
      uint32_t bu0 = (uint32_t)__shfl((int)u0, srcB);
      uint32_t bv0 = (uint32_t)__shfl((int)v0, srcB);
      uint32_t bu1 = (uint32_t)__shfl((int)u1, srcB);
      uint32_t bv1 = (uint32_t)__shfl((int)v1, srcB);
      union { uint32_t u[4]; bf16x8 v; } pb;
      pb.u[0] = stsel ? au1 : au0;
      pb.u[1] = stsel ? av1 : av0;
      pb.u[2] = stsel ? bu1 : bu0;
      pb.u[3] = stsel ? bv1 : bv0;
#pragma unroll
      for (int dt = 0; dt < 4; ++dt) {
        bf16x8 va = *(const bf16x8*)(Vt + (dt * 16 + l16) * VTS +
                                     jc * 32 + quad * 8);
        oacc[dt] = mfma16(va, pb.v, oacc[dt]);
      }
    }

    // O store via per-wave LDS bounce -> full 128B line stores
#pragma unroll
    for (int dt = 0; dt < 4; ++dt) {
      uint2 pk;
      pk.x = pack_bf2(oacc[dt][0] * inv, oacc[dt][1] * inv);
      pk.y = pack_bf2(oacc[dt][2] * inv, oacc[dt][3] * inv);
      *(uint2*)(ob + l16 * OBS + dt * 16 + quad * 4) = pk;
    }
    __asm__ __volatile__("s_waitcnt lgkmcnt(0)" ::: "memory");
#pragma unroll
    for (int rnd = 0; rnd < 4; ++rnd) {
      int q   = rnd * 4 + (lane >> 4);
      int o8  = lane & 15;
      uint2 d8 = *(const uint2*)(ob + q * OBS + o8 * 4);
      int qrow = mt * 16 + q;
      if (qrow < NTOK) {
        size_t obase = (size_t)(b * NTOK + qrow) * DIMC + h * HDIM;
        *(uint2*)(aout + obase + o8 * 4) = d8;
      }
    }
  }
}

// ---------------- launcher ----------------
extern "C" void kernel_launch(void* const* d_in, const int* in_sizes, int n_in,
                              void* d_out, int out_size, void* d_ws, size_t ws_size,
                              hipStream_t stream) {
  const float* x     = (const float*)d_in[0];
  const float* scale = (const float*)d_in[1];
  const float* wqkv  = (const float*)d_in[2];
  const float* wproj = (const float*)d_in[3];
  const float* bproj = (const float*)d_in[4];
  float* out = (float*)d_out;

  // ws layout (ushort). xb region now unused for x (A read f32 directly);
  // attb still aliases it.
  unsigned short* xb   = (unsigned short*)d_ws;
  unsigned short* wqb  = xb  + (size_t)MTOK * DIMC;
  unsigned short* wpb  = wqb + (size_t)QKVO * DIMC;
  unsigned short* qkvb = wpb + (size_t)DIMC * DIMC;
  unsigned short* attb = xb;                          // alias

  static bool attr_set = false;
  if (!attr_set) {
    hipFuncSetAttribute(reinterpret_cast<const void*>(gemm_qkv),
                        hipFuncAttributeMaxDynamicSharedMemorySize, 65536);
    hipFuncSetAttribute(reinterpret_cast<const void*>(gemm_proj),
                        hipFuncAttributeMaxDynamicSharedMemorySize, 49152);
    attr_set = true;
  }

  cvt_all<<<CVNB, 256, 0, stream>>>(wqkv, wproj, wqb, wpb);
  gemm_qkv<<<GMQ * GNQ, 256, 65536, stream>>>(x, wqb, qkvb);
  attn_fused<<<BH, 512, 0, stream>>>(qkvb, scale, attb);
  gemm_proj<<<GM64 * (DIMC / 128), 256, 49152, stream>>>(attb, wpb, bproj, x, out);
}

// Round 13
// 213.210 us; speedup vs baseline: 1.0033x; 1.0033x over previous
//
#include <hip/hip_runtime.h>
#include <cstdint>
#include <cstddef>

#define DEV static __device__ __forceinline__

typedef __attribute__((ext_vector_type(8))) short bf16x8;   // 8 bf16 (4 VGPRs)
typedef __attribute__((ext_vector_type(4))) float f32x4;

constexpr int NB   = 64;     // batch
constexpr int NTOK = 197;    // tokens
constexpr int DIMC = 768;    // channels
constexpr int NH   = 12;     // heads
constexpr int HDIM = 64;     // head dim
constexpr int MTOK = NB * NTOK;   // 12608 rows
constexpr int QKVO = 3 * DIMC;    // 2304
constexpr int BH   = NB * NH;     // 768
constexpr int VTS   = 232;        // V^T row stride (464B, 16B-aligned)
constexpr int OBS   = 68;         // O-bounce row stride (136B)
constexpr int GM64  = MTOK / 64;  // 197 M-tiles (64-row, exact)

// ---- qkv geometry (R5/R10, frozen): 128x128 tile, BK=64, 4 waves, dbuf, 2 blk/CU ----
// R12's fused-cvt A REVERTED (qkv 82-89 µs: reg-staging in the barrier path +
// doubled A fetch; m151 confirmed — gload_lds wins where linear LDS works).
// R11's BK=32 REVERTED (68 µs: per-kt granularity tax).
constexpr int GMQ  = (MTOK + 127) / 128;   // 99 M-tiles
constexpr int GNQ  = QKVO / 128;           // 18 N-tiles
constexpr int NKT  = DIMC / 64;            // 12 K-tiles
constexpr int HBUF = 16384;                // ushorts per buffer (A 8K + B 8K elems)

// ---- proj geometry (R6, frozen): 64x128 tile, BK=64, dbuf 48KB -> 3 blk/CU ----
constexpr int PBUF = 12288;                // ushorts per buffer (A 4K + B 8K elems)

DEV unsigned short f2bf(float f) {
  union { float f; uint32_t u; } v; v.f = f;
  uint32_t u = v.u;
  return (unsigned short)((u + 0x7FFFu + ((u >> 16) & 1u)) >> 16);  // RNE, finite
}

// R10: single-op packed f32->bf16 (RNE, bit-identical to f2bf on finite values).
DEV uint32_t pack_bf2(float a, float b) {
  uint32_t r;
  asm("v_cvt_pk_bf16_f32 %0, %1, %2" : "=v"(r) : "v"(a), "v"(b));
  return r;   // a -> bits 0..15, b -> bits 16..31
}

DEV f32x4 mfma16(bf16x8 a, bf16x8 b, f32x4 c) {
  return __builtin_amdgcn_mfma_f32_16x16x32_bf16(a, b, c, 0, 0, 0);
}

DEV void async_cp16(const unsigned short* g, unsigned short* l) {
  __builtin_amdgcn_global_load_lds(
      (__attribute__((address_space(1))) void*)g,
      (__attribute__((address_space(3))) void*)l, 16, 0, 0);
}

// supertile swizzle: groups of 16 M-tiles, N-major inside the group.
DEV void swizzle_idx(int lin, int gridM, int gridN, int& mt, int& nt) {
  int per = 16 * gridN;
  int sup = lin / per;
  int bm  = sup * 16;
  int Gm  = gridM - bm; if (Gm > 16) Gm = 16;
  int rem = lin - sup * per;
  nt = rem / Gm;
  mt = bm + (rem - nt * Gm);
}

// ---------------- f32 -> bf16 converts: one kernel, 4 float4/thread ----------------
constexpr int CVB1 = (MTOK * DIMC) / 4096;   // 2364
constexpr int CVB2 = (QKVO * DIMC) / 4096;   //  432
constexpr int CVB3 = (DIMC * DIMC) / 4096;   //  144
constexpr int CVNB = CVB1 + CVB2 + CVB3;     // 2940

__global__ void __launch_bounds__(256) cvt_all(const float* __restrict__ x,
                                               const float* __restrict__ wq,
                                               const float* __restrict__ wp,
                                               unsigned short* __restrict__ xb,
                                               unsigned short* __restrict__ wqb,
                                               unsigned short* __restrict__ wpb) {
  int blk = blockIdx.x;
  const float* s; unsigned short* d;
  if (blk < CVB1)               { s = x;  d = xb; }
  else if (blk < CVB1 + CVB2)   { s = wq; d = wqb; blk -= CVB1; }
  else                          { s = wp; d = wpb; blk -= CVB1 + CVB2; }
  size_t base = (size_t)blk * 4096 + (size_t)threadIdx.x * 4;
#pragma unroll
  for (int j = 0; j < 4; ++j) {
    size_t i = base + (size_t)j * 1024;
    float4 f = *(const float4*)(s + i);
    ushort4 o;
    o.x = f2bf(f.x); o.y = f2bf(f.y); o.z = f2bf(f.z); o.w = f2bf(f.w);
    *(ushort4*)(d + i) = o;
  }
}

// ---------------- QKV GEMM: 128x128 dbuf, R3-schedule, 2 blocks/CU (R5/R10 frozen) --
DEV void stage_mat(const unsigned short* src, unsigned short* dst,
                   int rbase, int k0, int clampR, int tid) {
#pragma unroll
  for (int u = 0; u < 4; ++u) {
    int c = u * 256 + tid;
    int row = c >> 3, cc = c & 7;
    int gr = rbase + row; gr = gr < clampR ? gr : clampR - 1;   // row clamp
    int gc = (cc ^ (row & 7)) * 8;
    async_cp16(src + (size_t)gr * DIMC + k0 + gc, dst + c * 8);
  }
}

template <int KK>
DEV void ldAB(const unsigned short* Ac, const unsigned short* Bc,
              int wm, int wn, int l16, int quad,
              bf16x8 (&af)[4], bf16x8 (&bf_)[4]) {
#pragma unroll
  for (int mi = 0; mi < 4; ++mi) {
    int r = wm * 64 + mi * 16 + l16;
    af[mi] = *(const bf16x8*)(Ac + r * 64 + (((KK * 4 + quad) ^ (r & 7)) * 8));
  }
#pragma unroll
  for (int ni = 0; ni < 4; ++ni) {
    int r = wn * 64 + ni * 16 + l16;
    bf_[ni] = *(const bf16x8*)(Bc + r * 64 + (((KK * 4 + quad) ^ (r & 7)) * 8));
  }
}

DEV void mm16(bf16x8 (&af)[4], bf16x8 (&bf_)[4], f32x4 (&acc)[4][4]) {
  __builtin_amdgcn_s_setprio(1);
#pragma unroll
  for (int mi = 0; mi < 4; ++mi)
#pragma unroll
    for (int ni = 0; ni < 4; ++ni)
      acc[mi][ni] = mfma16(af[mi], bf_[ni], acc[mi][ni]);
  __builtin_amdgcn_s_setprio(0);
}

__global__ void __launch_bounds__(256, 2) gemm_qkv(const unsigned short* __restrict__ A,
                                                   const unsigned short* __restrict__ Bw,
                                                   unsigned short* __restrict__ qkv) {
  extern __shared__ unsigned short lds[];   // 65536 B: 2 x [A 16KB | B 16KB]
  const int tid = threadIdx.x, lane = tid & 63, wave = tid >> 6;
  const int wm = wave & 1, wn = wave >> 1;        // 2M x 2N waves, 64x64 each
  const int l16 = lane & 15, quad = lane >> 4;
  int mt, nt;
  swizzle_idx(blockIdx.x, GMQ, GNQ, mt, nt);
  const int mbase = mt * 128, nbase = nt * 128;

  f32x4 acc[4][4];
#pragma unroll
  for (int i = 0; i < 4; ++i)
#pragma unroll
    for (int j = 0; j < 4; ++j) acc[i][j] = {0.f, 0.f, 0.f, 0.f};

  unsigned short* A0 = lds;
  unsigned short* B0 = lds + 8192;
  unsigned short* A1 = lds + HBUF;
  unsigned short* B1 = lds + HBUF + 8192;

  // prologue: stage kt0 into buf0, drain, barrier
  stage_mat(A,  A0, mbase, 0, MTOK, tid);
  stage_mat(Bw, B0, nbase, 0, QKVO, tid);
  asm volatile("s_waitcnt vmcnt(0)" ::: "memory");
  __builtin_amdgcn_s_barrier();

  for (int kt = 0; kt < NKT; ++kt) {
    const unsigned short* Ac = (kt & 1) ? A1 : A0;
    const unsigned short* Bc = (kt & 1) ? B1 : B0;
    unsigned short* An = (kt & 1) ? A0 : A1;
    unsigned short* Bn = (kt & 1) ? B0 : B1;

    // issue next K-tile's staging up front (next buffer only)
    if (kt + 1 < NKT) {
      int k0n = (kt + 1) * 64;
      stage_mat(A,  An, mbase, k0n, MTOK, tid);
      stage_mat(Bw, Bn, nbase, k0n, QKVO, tid);
    }

    // free-running compute; co-SIMD wave from the other block anti-phases
    bf16x8 af[4], bf_[4];
    ldAB<0>(Ac, Bc, wm, wn, l16, quad, af, bf_);
    mm16(af, bf_, acc);
    ldAB<1>(Ac, Bc, wm, wn, l16, quad, af, bf_);
    mm16(af, bf_, acc);

    // K-tile boundary: my stages landed + everyone done reading cur buf
    if (kt + 1 < NKT) {
      asm volatile("s_waitcnt vmcnt(0)" ::: "memory");
      __builtin_amdgcn_s_barrier();
    }
  }

  // epilogue: scatter to qkv bf16 [3][B][H][N][HD]
  const int oc64  = nbase + wn * 64;   // 64-aligned -> uniform which/h per wave
  const int which = oc64 / DIMC;
  const int h     = (oc64 % DIMC) / HDIM;
#pragma unroll
  for (int mi = 0; mi < 4; ++mi) {
    int t0 = mbase + wm * 64 + mi * 16 + quad * 4;
#pragma unroll
    for (int r = 0; r < 4; ++r) {
      int t = t0 + r;
      if (t < MTOK) {
        int b = t / NTOK, n = t - b * NTOK;
        size_t base = ((size_t)((which * NB + b) * NH + h) * NTOK + n) * HDIM;
#pragma unroll
        for (int ni = 0; ni < 4; ++ni)
          qkv[base + ni * 16 + l16] = f2bf(acc[mi][ni][r]);
      }
    }
  }
}

// ---------------- Proj GEMM (R6, frozen): 64x128 dbuf, 3 blocks/CU ----------------
DEV void stage_proj(const unsigned short* A, const unsigned short* Bw,
                    unsigned short* Abuf, unsigned short* Bbuf,
                    int mbase, int nbase, int k0, int tid) {
#pragma unroll
  for (int i = 0; i < 2; ++i) {          // A: 512 x 16B chunks (64 rows)
    int c = i * 256 + tid;
    int row = c >> 3, cc = c & 7;
    int gc = (cc ^ (row & 7)) * 8;
    async_cp16(A + (size_t)(mbase + row) * DIMC + k0 + gc, Abuf + c * 8);
  }
#pragma unroll
  for (int i = 0; i < 4; ++i) {          // B: 1024 x 16B chunks (128 rows)
    int c = i * 256 + tid;
    int row = c >> 3, cc = c & 7;
    int gc = (cc ^ (row & 7)) * 8;
    async_cp16(Bw + (size_t)(nbase + row) * DIMC + k0 + gc, Bbuf + c * 8);
  }
}

__global__ void __launch_bounds__(256, 3) gemm_proj(const unsigned short* __restrict__ A,
                                                    const unsigned short* __restrict__ Bw,
                                                    const float* __restrict__ bias,
                                                    const float* __restrict__ xres,
                                                    float* __restrict__ out) {
  extern __shared__ unsigned short lds[];   // 49152 B: 2 x [A 8KB | B 16KB]
  const int tid = threadIdx.x, lane = tid & 63, wave = tid >> 6;
  const int wm = wave & 1, wn = wave >> 1;
  const int l16 = lane & 15, quad = lane >> 4;
  int mt, nt;
  swizzle_idx(blockIdx.x, GM64, DIMC / 128, mt, nt);
  const int mbase = mt * 64, nbase = nt * 128;   // MTOK = 197*64 exactly: no tail

  f32x4 acc[2][4];
#pragma unroll
  for (int i = 0; i < 2; ++i)
#pragma unroll
    for (int j = 0; j < 4; ++j) acc[i][j] = {0.f, 0.f, 0.f, 0.f};

  unsigned short* A0 = lds;
  unsigned short* B0 = lds + 4096;
  unsigned short* A1 = lds + PBUF;
  unsigned short* B1 = lds + PBUF + 4096;

  // prologue
  stage_proj(A, Bw, A0, B0, mbase, nbase, 0, tid);
  asm volatile("s_waitcnt vmcnt(0)" ::: "memory");
  __builtin_amdgcn_s_barrier();

  for (int kt = 0; kt < NKT; ++kt) {
    const unsigned short* Ac = (kt & 1) ? A1 : A0;
    const unsigned short* Bc = (kt & 1) ? B1 : B0;
    unsigned short* An = (kt & 1) ? A0 : A1;
    unsigned short* Bn = (kt & 1) ? B0 : B1;

    if (kt + 1 < NKT)
      stage_proj(A, Bw, An, Bn, mbase, nbase, (kt + 1) * 64, tid);

#pragma unroll
    for (int kk = 0; kk < 64; kk += 32) {
      const int cw = (kk >> 3) + quad;
      bf16x8 af[2], bfr[4];
#pragma unroll
      for (int mi = 0; mi < 2; ++mi) {
        int r = wm * 32 + mi * 16 + l16;
        af[mi] = *(const bf16x8*)(Ac + r * 64 + ((cw ^ (r & 7)) * 8));
      }
#pragma unroll
      for (int ni = 0; ni < 4; ++ni) {
        int r = wn * 64 + ni * 16 + l16;
        bfr[ni] = *(const bf16x8*)(Bc + r * 64 + ((cw ^ (r & 7)) * 8));
      }
      __builtin_amdgcn_s_setprio(1);
#pragma unroll
      for (int mi = 0; mi < 2; ++mi)
#pragma unroll
        for (int ni = 0; ni < 4; ++ni)
          acc[mi][ni] = mfma16(af[mi], bfr[ni], acc[mi][ni]);
      __builtin_amdgcn_s_setprio(0);
    }

    if (kt + 1 < NKT) {
      asm volatile("s_waitcnt vmcnt(0)" ::: "memory");
      __builtin_amdgcn_s_barrier();
    }
  }

  const int oc = nbase + wn * 64;
#pragma unroll
  for (int mi = 0; mi < 2; ++mi) {
    int t0 = mbase + wm * 32 + mi * 16 + quad * 4;
#pragma unroll
    for (int r = 0; r < 4; ++r) {
      int t = t0 + r;                      // always < MTOK (exact tiling)
      size_t rowb = (size_t)t * DIMC;
#pragma unroll
      for (int ni = 0; ni < 4; ++ni) {
        int o = oc + ni * 16 + l16;
        out[rowb + o] = acc[mi][ni][r] + bias[o] + xres[rowb + o];
      }
    }
  }
}

// ---------------- fused attention (R13): 768 blocks x 8 waves, K from global -------
// R13: K LDS staging DROPPED (common-mistake #7 / m169): per-block K = 25 KB
// fits L1 (32 KB) and qkv is L2-hot. QK^T reads K fragments directly from
// global — a wave reads 16 full rows (whole 64B lines) per instruction;
// first touch L2-hit, then L1-resident across the 26x2 re-reads. LDS
// 72.4 -> 47.1 KB; occupancy unchanged (512 thr, 2 blk/CU, reg cap 128).
__global__ void __launch_bounds__(512, 2) attn_fused(const unsigned short* __restrict__ qkv,
                                                     const float* __restrict__ scale,
                                                     unsigned short* __restrict__ aout) {
  __shared__ __align__(16) unsigned short Vt[HDIM * VTS];        // 29696 B
  __shared__ __align__(16) unsigned short Ob[8 * 16 * OBS];      // 17408 B

  const int tid = threadIdx.x, lane = tid & 63, wave = tid >> 6;  // wave 0..7
  const int l16 = lane & 15, quad = lane >> 4;
  const int bh = blockIdx.x;
  const int b = bh / NH, h = bh - b * NH;

  const unsigned short* qg = qkv + (size_t)bh * (NTOK * HDIM);
  const unsigned short* kg = qkv + (size_t)(BH + bh) * (NTOK * HDIM);
  const unsigned short* vg = qkv + (size_t)(2 * BH + bh) * (NTOK * HDIM);
  const float sc = scale[h];

  // build V^T: coalesced 128B row reads + b128 writes at stride VTS
  {
    const int dcol = tid & 63;
    const int slab = tid >> 6;   // 0..7
#pragma unroll
    for (int p = 0; p < 4; ++p) {
      int n0 = p * 64 + slab * 8;
      if (n0 + 8 <= VTS) {       // PV reads cols < 224 only
        union { unsigned short us[8]; bf16x8 v; } tr;
#pragma unroll
        for (int i = 0; i < 8; ++i) {
          int n = n0 + i; n = n > NTOK - 1 ? NTOK - 1 : n;
          tr.us[i] = vg[(size_t)n * HDIM + dcol];
        }
        *(bf16x8*)(Vt + dcol * VTS + n0) = tr.v;
      }
    }
  }
  __syncthreads();

  const int srcA  = l16 + ((quad & 1) << 5);
  const int srcB  = srcA + 16;
  const int stsel = quad >> 1;
  unsigned short* ob = Ob + wave * (16 * OBS);

  for (int mt = wave; mt < 13; mt += 8) {
    int qr = mt * 16 + l16; if (qr > NTOK - 1) qr = NTOK - 1;
    bf16x8 qb0 = *(const bf16x8*)(qg + (size_t)qr * 64 + quad * 8);
    bf16x8 qb1 = *(const bf16x8*)(qg + (size_t)qr * 64 + 32 + quad * 8);
    const int mg = mt * 16 + l16;

    // batched S^T = K.Q^T (26 MFMAs; jc=6,st=1 keys all masked)
    // K fragments straight from global (L1-resident after first tile).
    f32x4 s[7][2];
#pragma unroll
    for (int jc = 0; jc < 7; ++jc)
#pragma unroll
      for (int st = 0; st < 2; ++st) {
        if (jc == 6 && st == 1) { s[6][1] = {0.f, 0.f, 0.f, 0.f}; continue; }
        int jrow = (jc * 2 + st) * 16 + l16;
        jrow = jrow > NTOK ? NTOK : jrow;      // row 197: in-ws garbage, masked
        const unsigned short* kr = kg + (size_t)jrow * 64;
        bf16x8 ka0 = *(const bf16x8*)(kr + quad * 8);
        bf16x8 ka1 = *(const bf16x8*)(kr + 32 + quad * 8);
        f32x4 t = {0.f, 0.f, 0.f, 0.f};
        t = mfma16(ka0, qb0, t);
        t = mfma16(ka1, qb1, t);
        s[jc][st] = t;
      }

    // softmax over keys (row = l16)
    float cmax = -1e30f;
#pragma unroll
    for (int jc = 0; jc < 7; ++jc)
#pragma unroll
      for (int st = 0; st < 2; ++st)
#pragma unroll
        for (int r = 0; r < 4; ++r) {
          int jg = jc * 32 + st * 16 + quad * 4 + r;
          float v = s[jc][st][r] * sc;
          v = (jg >= NTOK || jg == mg) ? -1e30f : v;
          s[jc][st][r] = v;
          cmax = fmaxf(cmax, v);
        }
    cmax = fmaxf(cmax, __shfl_xor(cmax, 16));
    cmax = fmaxf(cmax, __shfl_xor(cmax, 32));
    float psum = 0.f;
#pragma unroll
    for (int jc = 0; jc < 7; ++jc)
#pragma unroll
      for (int st = 0; st < 2; ++st)
#pragma unroll
        for (int r = 0; r < 4; ++r) {
          float e = __expf(s[jc][st][r] - cmax);
          psum += e;
          s[jc][st][r] = e;
        }
    psum += __shfl_xor(psum, 16);
    psum += __shfl_xor(psum, 32);
    const float inv = 1.0f / psum;

    // PV: O^T = V^T.P^T; P^T B-frags via shfl, V^T b128 from LDS
    f32x4 oacc[4];
#pragma unroll
    for (int dt = 0; dt < 4; ++dt) oacc[dt] = {0.f, 0.f, 0.f, 0.f};

#pragma unroll
    for (int jc = 0; jc < 7; ++jc) {
      uint32_t u0 = pack_bf2(s[jc][0][0], s[jc][0][1]);
      uint32_t v0 = pack_bf2(s[jc][0][2], s[jc][0][3]);
      uint32_t u1 = pack_bf2(s[jc][1][0], s[jc][1][1]);
      uint32_t v1 = pack_bf2(s[jc][1][2], s[jc][1][3]);
      uint32_t au0 = (uint32_t)__shfl((int)u0, srcA);
      uint32_t av0 = (uint32_t)__shfl((int)v0, srcA);
      uint32_t au1 = (uint32_t)__shfl((int)u1, srcA);
      uint32_t av1 = (uint32_t)__shfl((int)v1, srcA);
      uint32_t bu0 = (uint32_t)__shfl((int)u0, srcB);
      uint32_t bv0 = (uint32_t)__shfl((int)v0, srcB);
      uint32_t bu1 = (uint32_t)__shfl((int)u1, srcB);
      uint32_t bv1 = (uint32_t)__shfl((int)v1, srcB);
      union { uint32_t u[4]; bf16x8 v; } pb;
      pb.u[0] = stsel ? au1 : au0;
      pb.u[1] = stsel ? av1 : av0;
      pb.u[2] = stsel ? bu1 : bu0;
      pb.u[3] = stsel ? bv1 : bv0;
#pragma unroll
      for (int dt = 0; dt < 4; ++dt) {
        bf16x8 va = *(const bf16x8*)(Vt + (dt * 16 + l16) * VTS +
                                     jc * 32 + quad * 8);
        oacc[dt] = mfma16(va, pb.v, oacc[dt]);
      }
    }

    // O store via per-wave LDS bounce -> full 128B line stores
#pragma unroll
    for (int dt = 0; dt < 4; ++dt) {
      uint2 pk;
      pk.x = pack_bf2(oacc[dt][0] * inv, oacc[dt][1] * inv);
      pk.y = pack_bf2(oacc[dt][2] * inv, oacc[dt][3] * inv);
      *(uint2*)(ob + l16 * OBS + dt * 16 + quad * 4) = pk;
    }
    __asm__ __volatile__("s_waitcnt lgkmcnt(0)" ::: "memory");
#pragma unroll
    for (int rnd = 0; rnd < 4; ++rnd) {
      int q   = rnd * 4 + (lane >> 4);
      int o8  = lane & 15;
      uint2 d8 = *(const uint2*)(ob + q * OBS + o8 * 4);
      int qrow = mt * 16 + q;
      if (qrow < NTOK) {
        size_t obase = (size_t)(b * NTOK + qrow) * DIMC + h * HDIM;
        *(uint2*)(aout + obase + o8 * 4) = d8;
      }
    }
  }
}

// ---------------- launcher ----------------
extern "C" void kernel_launch(void* const* d_in, const int* in_sizes, int n_in,
                              void* d_out, int out_size, void* d_ws, size_t ws_size,
                              hipStream_t stream) {
  const float* x     = (const float*)d_in[0];
  const float* scale = (const float*)d_in[1];
  const float* wqkv  = (const float*)d_in[2];
  const float* wproj = (const float*)d_in[3];
  const float* bproj = (const float*)d_in[4];
  float* out = (float*)d_out;

  // ws layout (ushort), ~82.2 MB (R6-proven). attb aliases xb.
  unsigned short* xb   = (unsigned short*)d_ws;
  unsigned short* wqb  = xb  + (size_t)MTOK * DIMC;
  unsigned short* wpb  = wqb + (size_t)QKVO * DIMC;
  unsigned short* qkvb = wpb + (size_t)DIMC * DIMC;
  unsigned short* attb = xb;                          // alias

  static bool attr_set = false;
  if (!attr_set) {
    hipFuncSetAttribute(reinterpret_cast<const void*>(gemm_qkv),
                        hipFuncAttributeMaxDynamicSharedMemorySize, 65536);
    hipFuncSetAttribute(reinterpret_cast<const void*>(gemm_proj),
                        hipFuncAttributeMaxDynamicSharedMemorySize, 49152);
    attr_set = true;
  }

  cvt_all<<<CVNB, 256, 0, stream>>>(x, wqkv, wproj, xb, wqb, wpb);
  gemm_qkv<<<GMQ * GNQ, 256, 65536, stream>>>(xb, wqb, qkvb);
  attn_fused<<<BH, 512, 0, stream>>>(qkvb, scale, attb);
  gemm_proj<<<GM64 * (DIMC / 128), 256, 49152, stream>>>(attb, wpb, bproj, x, out);
}

// Round 14
// 197.034 us; speedup vs baseline: 1.0857x; 1.0821x over previous
//
#include <hip/hip_runtime.h>
#include <cstdint>
#include <cstddef>

#define DEV static __device__ __forceinline__

typedef __attribute__((ext_vector_type(8))) short bf16x8;   // 8 bf16 (4 VGPRs)
typedef __attribute__((ext_vector_type(4))) float f32x4;

constexpr int NB   = 64;     // batch
constexpr int NTOK = 197;    // tokens
constexpr int DIMC = 768;    // channels
constexpr int NH   = 12;     // heads
constexpr int HDIM = 64;     // head dim
constexpr int MTOK = NB * NTOK;   // 12608 rows
constexpr int QKVO = 3 * DIMC;    // 2304
constexpr int BH   = NB * NH;     // 768
constexpr int KROWS = 198;        // staged K rows (jrow clamped to 197)
constexpr int VTS   = 232;        // V^T row stride (464B, 16B-aligned)
constexpr int OBS   = 68;         // O-bounce row stride (136B)
constexpr int GM64  = MTOK / 64;  // 197 M-tiles (64-row, exact)

// ---- qkv geometry (R5/R10, FINAL): 128x128 tile, BK=64, 4 waves, dbuf, 2 blk/CU ----
// Session record: 6 qkv schedules bracket 55-85 µs (this is the floor);
// R9 XCD-remap no effect; R11 BK=32 granularity tax (68); R12 fused-cvt A
// regression (82-89); R13 attn K-from-global regression (L1 thrash). This
// file is the measured optimum (R10, 199.4 µs).
constexpr int GMQ  = (MTOK + 127) / 128;   // 99 M-tiles
constexpr int GNQ  = QKVO / 128;           // 18 N-tiles
constexpr int NKT  = DIMC / 64;            // 12 K-tiles
constexpr int HBUF = 16384;                // ushorts per buffer (A 8K + B 8K elems)

// ---- proj geometry (R6, frozen): 64x128 tile, BK=64, dbuf 48KB -> 3 blk/CU ----
constexpr int PBUF = 12288;                // ushorts per buffer (A 4K + B 8K elems)

DEV unsigned short f2bf(float f) {
  union { float f; uint32_t u; } v; v.f = f;
  uint32_t u = v.u;
  return (unsigned short)((u + 0x7FFFu + ((u >> 16) & 1u)) >> 16);  // RNE, finite
}

// R10: single-op packed f32->bf16 (RNE, bit-identical to f2bf on finite values).
DEV uint32_t pack_bf2(float a, float b) {
  uint32_t r;
  asm("v_cvt_pk_bf16_f32 %0, %1, %2" : "=v"(r) : "v"(a), "v"(b));
  return r;   // a -> bits 0..15, b -> bits 16..31
}

DEV f32x4 mfma16(bf16x8 a, bf16x8 b, f32x4 c) {
  return __builtin_amdgcn_mfma_f32_16x16x32_bf16(a, b, c, 0, 0, 0);
}

DEV void async_cp16(const unsigned short* g, unsigned short* l) {
  __builtin_amdgcn_global_load_lds(
      (__attribute__((address_space(1))) void*)g,
      (__attribute__((address_space(3))) void*)l, 16, 0, 0);
}

// supertile swizzle: groups of 16 M-tiles, N-major inside the group.
DEV void swizzle_idx(int lin, int gridM, int gridN, int& mt, int& nt) {
  int per = 16 * gridN;
  int sup = lin / per;
  int bm  = sup * 16;
  int Gm  = gridM - bm; if (Gm > 16) Gm = 16;
  int rem = lin - sup * per;
  nt = rem / Gm;
  mt = bm + (rem - nt * Gm);
}

// ---------------- f32 -> bf16 converts: one kernel, 4 float4/thread ----------------
constexpr int CVB1 = (MTOK * DIMC) / 4096;   // 2364
constexpr int CVB2 = (QKVO * DIMC) / 4096;   //  432
constexpr int CVB3 = (DIMC * DIMC) / 4096;   //  144
constexpr int CVNB = CVB1 + CVB2 + CVB3;     // 2940

__global__ void __launch_bounds__(256) cvt_all(const float* __restrict__ x,
                                               const float* __restrict__ wq,
                                               const float* __restrict__ wp,
                                               unsigned short* __restrict__ xb,
                                               unsigned short* __restrict__ wqb,
                                               unsigned short* __restrict__ wpb) {
  int blk = blockIdx.x;
  const float* s; unsigned short* d;
  if (blk < CVB1)               { s = x;  d = xb; }
  else if (blk < CVB1 + CVB2)   { s = wq; d = wqb; blk -= CVB1; }
  else                          { s = wp; d = wpb; blk -= CVB1 + CVB2; }
  size_t base = (size_t)blk * 4096 + (size_t)threadIdx.x * 4;
#pragma unroll
  for (int j = 0; j < 4; ++j) {
    size_t i = base + (size_t)j * 1024;
    float4 f = *(const float4*)(s + i);
    ushort4 o;
    o.x = f2bf(f.x); o.y = f2bf(f.y); o.z = f2bf(f.z); o.w = f2bf(f.w);
    *(ushort4*)(d + i) = o;
  }
}

// ---------------- QKV GEMM: 128x128 dbuf, R3-schedule, 2 blocks/CU (R5/R10) ------
DEV void stage_mat(const unsigned short* src, unsigned short* dst,
                   int rbase, int k0, int clampR, int tid) {
#pragma unroll
  for (int u = 0; u < 4; ++u) {
    int c = u * 256 + tid;
    int row = c >> 3, cc = c & 7;
    int gr = rbase + row; gr = gr < clampR ? gr : clampR - 1;   // row clamp
    int gc = (cc ^ (row & 7)) * 8;
    async_cp16(src + (size_t)gr * DIMC + k0 + gc, dst + c * 8);
  }
}

template <int KK>
DEV void ldAB(const unsigned short* Ac, const unsigned short* Bc,
              int wm, int wn, int l16, int quad,
              bf16x8 (&af)[4], bf16x8 (&bf_)[4]) {
#pragma unroll
  for (int mi = 0; mi < 4; ++mi) {
    int r = wm * 64 + mi * 16 + l16;
    af[mi] = *(const bf16x8*)(Ac + r * 64 + (((KK * 4 + quad) ^ (r & 7)) * 8));
  }
#pragma unroll
  for (int ni = 0; ni < 4; ++ni) {
    int r = wn * 64 + ni * 16 + l16;
    bf_[ni] = *(const bf16x8*)(Bc + r * 64 + (((KK * 4 + quad) ^ (r & 7)) * 8));
  }
}

DEV void mm16(bf16x8 (&af)[4], bf16x8 (&bf_)[4], f32x4 (&acc)[4][4]) {
  __builtin_amdgcn_s_setprio(1);
#pragma unroll
  for (int mi = 0; mi < 4; ++mi)
#pragma unroll
    for (int ni = 0; ni < 4; ++ni)
      acc[mi][ni] = mfma16(af[mi], bf_[ni], acc[mi][ni]);
  __builtin_amdgcn_s_setprio(0);
}

__global__ void __launch_bounds__(256, 2) gemm_qkv(const unsigned short* __restrict__ A,
                                                   const unsigned short* __restrict__ Bw,
                                                   unsigned short* __restrict__ qkv) {
  extern __shared__ unsigned short lds[];   // 65536 B: 2 x [A 16KB | B 16KB]
  const int tid = threadIdx.x, lane = tid & 63, wave = tid >> 6;
  const int wm = wave & 1, wn = wave >> 1;        // 2M x 2N waves, 64x64 each
  const int l16 = lane & 15, quad = lane >> 4;
  int mt, nt;
  swizzle_idx(blockIdx.x, GMQ, GNQ, mt, nt);
  const int mbase = mt * 128, nbase = nt * 128;

  f32x4 acc[4][4];
#pragma unroll
  for (int i = 0; i < 4; ++i)
#pragma unroll
    for (int j = 0; j < 4; ++j) acc[i][j] = {0.f, 0.f, 0.f, 0.f};

  unsigned short* A0 = lds;
  unsigned short* B0 = lds + 8192;
  unsigned short* A1 = lds + HBUF;
  unsigned short* B1 = lds + HBUF + 8192;

  // prologue: stage kt0 into buf0, drain, barrier
  stage_mat(A,  A0, mbase, 0, MTOK, tid);
  stage_mat(Bw, B0, nbase, 0, QKVO, tid);
  asm volatile("s_waitcnt vmcnt(0)" ::: "memory");
  __builtin_amdgcn_s_barrier();

  for (int kt = 0; kt < NKT; ++kt) {
    const unsigned short* Ac = (kt & 1) ? A1 : A0;
    const unsigned short* Bc = (kt & 1) ? B1 : B0;
    unsigned short* An = (kt & 1) ? A0 : A1;
    unsigned short* Bn = (kt & 1) ? B0 : B1;

    // issue next K-tile's staging up front (next buffer only)
    if (kt + 1 < NKT) {
      int k0n = (kt + 1) * 64;
      stage_mat(A,  An, mbase, k0n, MTOK, tid);
      stage_mat(Bw, Bn, nbase, k0n, QKVO, tid);
    }

    // free-running compute; co-SIMD wave from the other block anti-phases
    bf16x8 af[4], bf_[4];
    ldAB<0>(Ac, Bc, wm, wn, l16, quad, af, bf_);
    mm16(af, bf_, acc);
    ldAB<1>(Ac, Bc, wm, wn, l16, quad, af, bf_);
    mm16(af, bf_, acc);

    // K-tile boundary: my stages landed + everyone done reading cur buf
    if (kt + 1 < NKT) {
      asm volatile("s_waitcnt vmcnt(0)" ::: "memory");
      __builtin_amdgcn_s_barrier();
    }
  }

  // epilogue: scatter to qkv bf16 [3][B][H][N][HD]
  const int oc64  = nbase + wn * 64;   // 64-aligned -> uniform which/h per wave
  const int which = oc64 / DIMC;
  const int h     = (oc64 % DIMC) / HDIM;
#pragma unroll
  for (int mi = 0; mi < 4; ++mi) {
    int t0 = mbase + wm * 64 + mi * 16 + quad * 4;
#pragma unroll
    for (int r = 0; r < 4; ++r) {
      int t = t0 + r;
      if (t < MTOK) {
        int b = t / NTOK, n = t - b * NTOK;
        size_t base = ((size_t)((which * NB + b) * NH + h) * NTOK + n) * HDIM;
#pragma unroll
        for (int ni = 0; ni < 4; ++ni)
          qkv[base + ni * 16 + l16] = f2bf(acc[mi][ni][r]);
      }
    }
  }
}

// ---------------- Proj GEMM (R6, frozen): 64x128 dbuf, 3 blocks/CU ----------------
DEV void stage_proj(const unsigned short* A, const unsigned short* Bw,
                    unsigned short* Abuf, unsigned short* Bbuf,
                    int mbase, int nbase, int k0, int tid) {
#pragma unroll
  for (int i = 0; i < 2; ++i) {          // A: 512 x 16B chunks (64 rows)
    int c = i * 256 + tid;
    int row = c >> 3, cc = c & 7;
    int gc = (cc ^ (row & 7)) * 8;
    async_cp16(A + (size_t)(mbase + row) * DIMC + k0 + gc, Abuf + c * 8);
  }
#pragma unroll
  for (int i = 0; i < 4; ++i) {          // B: 1024 x 16B chunks (128 rows)
    int c = i * 256 + tid;
    int row = c >> 3, cc = c & 7;
    int gc = (cc ^ (row & 7)) * 8;
    async_cp16(Bw + (size_t)(nbase + row) * DIMC + k0 + gc, Bbuf + c * 8);
  }
}

__global__ void __launch_bounds__(256, 3) gemm_proj(const unsigned short* __restrict__ A,
                                                    const unsigned short* __restrict__ Bw,
                                                    const float* __restrict__ bias,
                                                    const float* __restrict__ xres,
                                                    float* __restrict__ out) {
  extern __shared__ unsigned short lds[];   // 49152 B: 2 x [A 8KB | B 16KB]
  const int tid = threadIdx.x, lane = tid & 63, wave = tid >> 6;
  const int wm = wave & 1, wn = wave >> 1;
  const int l16 = lane & 15, quad = lane >> 4;
  int mt, nt;
  swizzle_idx(blockIdx.x, GM64, DIMC / 128, mt, nt);
  const int mbase = mt * 64, nbase = nt * 128;   // MTOK = 197*64 exactly: no tail

  f32x4 acc[2][4];
#pragma unroll
  for (int i = 0; i < 2; ++i)
#pragma unroll
    for (int j = 0; j < 4; ++j) acc[i][j] = {0.f, 0.f, 0.f, 0.f};

  unsigned short* A0 = lds;
  unsigned short* B0 = lds + 4096;
  unsigned short* A1 = lds + PBUF;
  unsigned short* B1 = lds + PBUF + 4096;

  // prologue
  stage_proj(A, Bw, A0, B0, mbase, nbase, 0, tid);
  asm volatile("s_waitcnt vmcnt(0)" ::: "memory");
  __builtin_amdgcn_s_barrier();

  for (int kt = 0; kt < NKT; ++kt) {
    const unsigned short* Ac = (kt & 1) ? A1 : A0;
    const unsigned short* Bc = (kt & 1) ? B1 : B0;
    unsigned short* An = (kt & 1) ? A0 : A1;
    unsigned short* Bn = (kt & 1) ? B0 : B1;

    if (kt + 1 < NKT)
      stage_proj(A, Bw, An, Bn, mbase, nbase, (kt + 1) * 64, tid);

#pragma unroll
    for (int kk = 0; kk < 64; kk += 32) {
      const int cw = (kk >> 3) + quad;
      bf16x8 af[2], bfr[4];
#pragma unroll
      for (int mi = 0; mi < 2; ++mi) {
        int r = wm * 32 + mi * 16 + l16;
        af[mi] = *(const bf16x8*)(Ac + r * 64 + ((cw ^ (r & 7)) * 8));
      }
#pragma unroll
      for (int ni = 0; ni < 4; ++ni) {
        int r = wn * 64 + ni * 16 + l16;
        bfr[ni] = *(const bf16x8*)(Bc + r * 64 + ((cw ^ (r & 7)) * 8));
      }
      __builtin_amdgcn_s_setprio(1);
#pragma unroll
      for (int mi = 0; mi < 2; ++mi)
#pragma unroll
        for (int ni = 0; ni < 4; ++ni)
          acc[mi][ni] = mfma16(af[mi], bfr[ni], acc[mi][ni]);
      __builtin_amdgcn_s_setprio(0);
    }

    if (kt + 1 < NKT) {
      asm volatile("s_waitcnt vmcnt(0)" ::: "memory");
      __builtin_amdgcn_s_barrier();
    }
  }

  const int oc = nbase + wn * 64;
#pragma unroll
  for (int mi = 0; mi < 2; ++mi) {
    int t0 = mbase + wm * 32 + mi * 16 + quad * 4;
#pragma unroll
    for (int r = 0; r < 4; ++r) {
      int t = t0 + r;                      // always < MTOK (exact tiling)
      size_t rowb = (size_t)t * DIMC;
#pragma unroll
      for (int ni = 0; ni < 4; ++ni) {
        int o = oc + ni * 16 + l16;
        out[rowb + o] = acc[mi][ni][r] + bias[o] + xres[rowb + o];
      }
    }
  }
}

// ---------------- fused attention (R8 + R10 cvt_pk, FINAL): 768 blocks x 8 waves ----
__global__ void __launch_bounds__(512, 2) attn_fused(const unsigned short* __restrict__ qkv,
                                                     const float* __restrict__ scale,
                                                     unsigned short* __restrict__ aout) {
  __shared__ __align__(16) unsigned short Ks[KROWS * 64];        // 25344 B
  __shared__ __align__(16) unsigned short Vt[HDIM * VTS];        // 29696 B
  __shared__ __align__(16) unsigned short Ob[8 * 16 * OBS];      // 17408 B

  const int tid = threadIdx.x, lane = tid & 63, wave = tid >> 6;  // wave 0..7
  const int l16 = lane & 15, quad = lane >> 4;
  const int bh = blockIdx.x;
  const int b = bh / NH, h = bh - b * NH;

  const unsigned short* qg = qkv + (size_t)bh * (NTOK * HDIM);
  const unsigned short* kg = qkv + (size_t)(BH + bh) * (NTOK * HDIM);
  const unsigned short* vg = qkv + (size_t)(2 * BH + bh) * (NTOK * HDIM);
  const float sc = scale[h];

  // stage K via DMA: rows 0..197 (1584 chunks over 512 threads)
#pragma unroll
  for (int i = 0; i < 4; ++i) {
    int c = i * 512 + tid;
    if (c < KROWS * 8) {
      int row = c >> 3, cc = c & 7;
      async_cp16(kg + (size_t)row * 64 + ((cc ^ (row & 7)) * 8), Ks + c * 8);
    }
  }
  // build V^T: coalesced 128B row reads + b128 writes at stride VTS
  {
    const int dcol = tid & 63;
    const int slab = tid >> 6;   // 0..7
#pragma unroll
    for (int p = 0; p < 4; ++p) {
      int n0 = p * 64 + slab * 8;
      if (n0 + 8 <= VTS) {       // PV reads cols < 224 only
        union { unsigned short us[8]; bf16x8 v; } tr;
#pragma unroll
        for (int i = 0; i < 8; ++i) {
          int n = n0 + i; n = n > NTOK - 1 ? NTOK - 1 : n;
          tr.us[i] = vg[(size_t)n * HDIM + dcol];
        }
        *(bf16x8*)(Vt + dcol * VTS + n0) = tr.v;
      }
    }
  }
  __syncthreads();

  const int srcA  = l16 + ((quad & 1) << 5);
  const int srcB  = srcA + 16;
  const int stsel = quad >> 1;
  unsigned short* ob = Ob + wave * (16 * OBS);

  for (int mt = wave; mt < 13; mt += 8) {
    int qr = mt * 16 + l16; if (qr > NTOK - 1) qr = NTOK - 1;
    bf16x8 qb0 = *(const bf16x8*)(qg + (size_t)qr * 64 + quad * 8);
    bf16x8 qb1 = *(const bf16x8*)(qg + (size_t)qr * 64 + 32 + quad * 8);
    const int mg = mt * 16 + l16;

    // batched S^T = K.Q^T (26 MFMAs; jc=6,st=1 keys all masked)
    f32x4 s[7][2];
#pragma unroll
    for (int jc = 0; jc < 7; ++jc)
#pragma unroll
      for (int st = 0; st < 2; ++st) {
        if (jc == 6 && st == 1) { s[6][1] = {0.f, 0.f, 0.f, 0.f}; continue; }
        int jrow = (jc * 2 + st) * 16 + l16;
        jrow = jrow > NTOK ? NTOK : jrow;
        const unsigned short* kr = Ks + jrow * 64;
        bf16x8 ka0 = *(const bf16x8*)(kr + (quad       ^ (jrow & 7)) * 8);
        bf16x8 ka1 = *(const bf16x8*)(kr + ((4 + quad) ^ (jrow & 7)) * 8);
        f32x4 t = {0.f, 0.f, 0.f, 0.f};
        t = mfma16(ka0, qb0, t);
        t = mfma16(ka1, qb1, t);
        s[jc][st] = t;
      }

    // softmax over keys (row = l16)
    float cmax = -1e30f;
#pragma unroll
    for (int jc = 0; jc < 7; ++jc)
#pragma unroll
      for (int st = 0; st < 2; ++st)
#pragma unroll
        for (int r = 0; r < 4; ++r) {
          int jg = jc * 32 + st * 16 + quad * 4 + r;
          float v = s[jc][st][r] * sc;
          v = (jg >= NTOK || jg == mg) ? -1e30f : v;
          s[jc][st][r] = v;
          cmax = fmaxf(cmax, v);
        }
    cmax = fmaxf(cmax, __shfl_xor(cmax, 16));
    cmax = fmaxf(cmax, __shfl_xor(cmax, 32));
    float psum = 0.f;
#pragma unroll
    for (int jc = 0; jc < 7; ++jc)
#pragma unroll
      for (int st = 0; st < 2; ++st)
#pragma unroll
        for (int r = 0; r < 4; ++r) {
          float e = __expf(s[jc][st][r] - cmax);
          psum += e;
          s[jc][st][r] = e;
        }
    psum += __shfl_xor(psum, 16);
    psum += __shfl_xor(psum, 32);
    const float inv = 1.0f / psum;

    // PV: O^T = V^T.P^T; P^T B-frags via shfl, V^T b128 from LDS
    f32x4 oacc[4];
#pragma unroll
    for (int dt = 0; dt < 4; ++dt) oacc[dt] = {0.f, 0.f, 0.f, 0.f};

#pragma unroll
    for (int jc = 0; jc < 7; ++jc) {
      uint32_t u0 = pack_bf2(s[jc][0][0], s[jc][0][1]);
      uint32_t v0 = pack_bf2(s[jc][0][2], s[jc][0][3]);
      uint32_t u1 = pack_bf2(s[jc][1][0], s[jc][1][1]);
      uint32_t v1 = pack_bf2(s[jc][1][2], s[jc][1][3]);
      uint32_t au0 = (uint32_t)__shfl((int)u0, srcA);
      uint32_t av0 = (uint32_t)__shfl((int)v0, srcA);
      uint32_t au1 = (uint32_t)__shfl((int)u1, srcA);
      uint32_t av1 = (uint32_t)__shfl((int)v1, srcA);
      uint32_t bu0 = (uint32_t)__shfl((int)u0, srcB);
      uint32_t bv0 = (uint32_t)__shfl((int)v0, srcB);
      uint32_t bu1 = (uint32_t)__shfl((int)u1, srcB);
      uint32_t bv1 = (uint32_t)__shfl((int)v1, srcB);
      union { uint32_t u[4]; bf16x8 v; } pb;
      pb.u[0] = stsel ? au1 : au0;
      pb.u[1] = stsel ? av1 : av0;
      pb.u[2] = stsel ? bu1 : bu0;
      pb.u[3] = stsel ? bv1 : bv0;
#pragma unroll
      for (int dt = 0; dt < 4; ++dt) {
        bf16x8 va = *(const bf16x8*)(Vt + (dt * 16 + l16) * VTS +
                                     jc * 32 + quad * 8);
        oacc[dt] = mfma16(va, pb.v, oacc[dt]);
      }
    }

    // O store via per-wave LDS bounce -> full 128B line stores
#pragma unroll
    for (int dt = 0; dt < 4; ++dt) {
      uint2 pk;
      pk.x = pack_bf2(oacc[dt][0] * inv, oacc[dt][1] * inv);
      pk.y = pack_bf2(oacc[dt][2] * inv, oacc[dt][3] * inv);
      *(uint2*)(ob + l16 * OBS + dt * 16 + quad * 4) = pk;
    }
    __asm__ __volatile__("s_waitcnt lgkmcnt(0)" ::: "memory");
#pragma unroll
    for (int rnd = 0; rnd < 4; ++rnd) {
      int q   = rnd * 4 + (lane >> 4);
      int o8  = lane & 15;
      uint2 d8 = *(const uint2*)(ob + q * OBS + o8 * 4);
      int qrow = mt * 16 + q;
      if (qrow < NTOK) {
        size_t obase = (size_t)(b * NTOK + qrow) * DIMC + h * HDIM;
        *(uint2*)(aout + obase + o8 * 4) = d8;
      }
    }
  }
}

// ---------------- launcher ----------------
extern "C" void kernel_launch(void* const* d_in, const int* in_sizes, int n_in,
                              void* d_out, int out_size, void* d_ws, size_t ws_size,
                              hipStream_t stream) {
  const float* x     = (const float*)d_in[0];
  const float* scale = (const float*)d_in[1];
  const float* wqkv  = (const float*)d_in[2];
  const float* wproj = (const float*)d_in[3];
  const float* bproj = (const float*)d_in[4];
  float* out = (float*)d_out;

  // ws layout (ushort), ~82.2 MB (R6-proven). attb aliases xb.
  unsigned short* xb   = (unsigned short*)d_ws;
  unsigned short* wqb  = xb  + (size_t)MTOK * DIMC;
  unsigned short* wpb  = wqb + (size_t)QKVO * DIMC;
  unsigned short* qkvb = wpb + (size_t)DIMC * DIMC;
  unsigned short* attb = xb;                          // alias

  static bool attr_set = false;
  if (!attr_set) {
    hipFuncSetAttribute(reinterpret_cast<const void*>(gemm_qkv),
                        hipFuncAttributeMaxDynamicSharedMemorySize, 65536);
    hipFuncSetAttribute(reinterpret_cast<const void*>(gemm_proj),
                        hipFuncAttributeMaxDynamicSharedMemorySize, 49152);
    attr_set = true;
  }

  cvt_all<<<CVNB, 256, 0, stream>>>(x, wqkv, wproj, xb, wqb, wpb);
  gemm_qkv<<<GMQ * GNQ, 256, 65536, stream>>>(xb, wqb, qkvb);
  attn_fused<<<BH, 512, 0, stream>>>(qkvb, scale, attb);
  gemm_proj<<<GM64 * (DIMC / 128), 256, 49152, stream>>>(attb, wpb, bproj, x, out);
}